// Round 7
// baseline (122.808 us; speedup 1.0000x reference)
//
#include <hip/hip_runtime.h>

// MultiAgentLinearLayer via bf16 MFMA, round 8 (resubmit — R6 bench was an
// infra container failure, no data): NO X staging — A-frags loaded directly
// from global (L2) inside the K-loop.
// out[b,o] = sum_k W[agent[b],o,k]*x[b,k] + bias[agent[b],o]
// B=2048, I=O=512, 64 agents, fp32 in/out. Threshold 5.97e-2 permits bf16.
//
// Evidence trail: R4=104.6 best; R5 (8 waves/CU)=113.9; R6 (6-deep prime)=
// 104.9 neutral; R7 (pipelined staging)=105.0 neutral. Three latency-hiding
// reorderings of the X staging path all neutral => the cost is the staging
// WORK + BARRIERS, not its latency. R8 deletes the path: X is 64KB/agent,
// L2-resident under the XCD swizzle; the 8 n-waves share it through L2
// instead of LDS. Each lane computes its frag-row pointer once per chunk
// (rowlist[i*16+nl], clamped), then the unrolled K-loop does constant-offset
// dwordx4 pairs + cvt_pk -> MFMA A operand. Staging rounds, 16 cvt_pk, 8
// ds_writes, 65KB Xs and 2 of 4 barriers disappear; X traffic overlaps the
// W stream. Cost: X read 2x from L2 (256KB/block), +8 cvt_pk per k-iter.
// Numerics identical (same RNE pairs, same accumulation order).
// Kept from R4: 16 waves, kh-split + Rs(17) reduction, XCD swizzle, nfrag
// guard, 3-deep W prime, which-first.

constexpr int BATCH  = 2048;
constexpr int NAGENT = 64;
constexpr int IN_F   = 512;
constexpr int OUT_F  = 512;

constexpr int BN  = 128;        // block n-tile
constexpr int MCH = 64;         // m rows per chunk (count<=64 in practice)

typedef __attribute__((ext_vector_type(8))) short short8;     // bf16 A/B frag
typedef __attribute__((ext_vector_type(4))) float f32x4;      // fp32 C/D frag
typedef __attribute__((ext_vector_type(4))) unsigned int u32x4;
typedef __bf16 bf16x2 __attribute__((ext_vector_type(2)));

__device__ inline unsigned pk_bf(float lo, float hi) {
  bf16x2 v;
  v[0] = (__bf16)lo;
  v[1] = (__bf16)hi;
  return __builtin_bit_cast(unsigned, v);   // v_cvt_pk_bf16_f32, RNE
}

__global__ __launch_bounds__(1024, 4) void agent_linear_mfma8(
    const int*   __restrict__ which,
    const float* __restrict__ x,
    const float* __restrict__ weight,
    const float* __restrict__ bias,
    float*       __restrict__ out) {
  const int tid   = threadIdx.x;
  const int lane  = tid & 63;
  const int wid   = tid >> 6;        // 0..15
  const int w8    = wid & 7;         // n-wave within BN
  const int kh    = wid >> 3;        // k-half: 0 or 1

  // bid = (a&7) + 8*n + 32*(a>>3): agent a's 4 n-tiles all share bid%8
  const int bid   = blockIdx.x;      // 0..255
  const int agent = (bid & 7) | ((bid >> 5) << 3);
  const int obase = ((bid >> 3) & 3) * BN;

  __shared__ int rowlist_s[BATCH];                       // 8 KB
  __shared__ int wsum_s[16];
  __shared__ float Rs[8][MCH][17];                       // 34 KB, k-half partials

  // ---- issue `which` load first (longest dependent chain) ----
  int2 v = ((const int2*)which)[tid];                    // 2 vals/thread

  const int nl = lane & 15;      // n within frag / m within A-frag
  const int kq = lane >> 4;      // k-quad 0..3

  const float* wp = weight + ((size_t)(agent * OUT_F + obase + w8 * 16 + nl)) * IN_F
                  + kh * 256 + kq * 8;

  // ---- prime 3-deep W prefetch (depth beyond 3 proven neutral R6) ----
  float4 pa[3], pb[3];
#pragma unroll
  for (int j = 0; j < 3; ++j) {
    pa[j] = *(const float4*)(wp + j * 32);
    pb[j] = *(const float4*)(wp + j * 32 + 4);
  }

  const float bv = bias[agent * OUT_F + obase + w8 * 16 + nl];

  // ---- stable compaction: rows with which[i]==agent, ascending ----
  int lc = (v.x == agent) + (v.y == agent);
  int s = lc;
#pragma unroll
  for (int off = 1; off < 64; off <<= 1) {
    int t = __shfl_up(s, off);
    if (lane >= off) s += t;
  }
  if (lane == 63) wsum_s[wid] = s;
  __syncthreads();
  int base = 0, count = 0;
#pragma unroll
  for (int w = 0; w < 16; ++w) {
    int ws = wsum_s[w];
    if (w < wid) base += ws;
    count += ws;
  }
  {
    int pos = base + s - lc;
    if (v.x == agent) rowlist_s[pos++] = 2 * tid;
    if (v.y == agent) rowlist_s[pos]   = 2 * tid + 1;
  }

  for (int m0 = 0; m0 < count; m0 += MCH) {
    const int mcount = min(MCH, count - m0);
    const int nfrag  = (mcount + 15) >> 4;   // live 16-row A-frags (1..4)

    // iter0: rowlist ready; later iters: prior epilogue's Rs reads done
    __syncthreads();

    // ---- per-lane A-frag row pointers (clamped to a live row) ----
    const float* xp[4];
#pragma unroll
    for (int i = 0; i < 4; ++i) {
      int m  = i * 16 + nl;
      int mm = (m < mcount) ? m : 0;           // dead slots read row 0 (masked later)
      xp[i] = x + (size_t)rowlist_s[m0 + mm] * IN_F + kh * 256 + kq * 8;
    }

    // ---- barrier-free K-loop over this wave's 256-k half ----
    // A operands come straight from global (L2-resident, 4 blocks/agent share).
    f32x4 acc[4] = {{0.f,0.f,0.f,0.f},{0.f,0.f,0.f,0.f},
                    {0.f,0.f,0.f,0.f},{0.f,0.f,0.f,0.f}};
#pragma unroll
    for (int k = 0; k < 8; ++k) {
      float4 c0 = pa[k % 3], c1 = pb[k % 3];
      if (k + 3 < 8) {
        pa[k % 3] = *(const float4*)(wp + (k + 3) * 32);
        pb[k % 3] = *(const float4*)(wp + (k + 3) * 32 + 4);
      }
      u32x4 q;
      q[0] = pk_bf(c0.x, c0.y); q[1] = pk_bf(c0.z, c0.w);
      q[2] = pk_bf(c1.x, c1.y); q[3] = pk_bf(c1.z, c1.w);
      short8 bfr = __builtin_bit_cast(short8, q);
#pragma unroll
      for (int i = 0; i < 4; ++i) {
        if (i < nfrag) {   // wave-uniform: skip dead-row frags entirely
          float4 a0 = *(const float4*)(xp[i] + k * 32);
          float4 a1 = *(const float4*)(xp[i] + k * 32 + 4);
          u32x4 qa;
          qa[0] = pk_bf(a0.x, a0.y); qa[1] = pk_bf(a0.z, a0.w);
          qa[2] = pk_bf(a1.x, a1.y); qa[3] = pk_bf(a1.z, a1.w);
          short8 af = __builtin_bit_cast(short8, qa);
          acc[i] = __builtin_amdgcn_mfma_f32_16x16x32_bf16(af, bfr, acc[i], 0, 0, 0);
        }
      }
    }

    // ---- cross-k-half reduction: upper waves park partials in LDS ----
    if (kh == 1) {
#pragma unroll
      for (int i = 0; i < 4; ++i)
        if (i < nfrag)
#pragma unroll
          for (int r = 0; r < 4; ++r)
            Rs[w8][i * 16 + kq * 4 + r][nl] = acc[i][r];
    }
    __syncthreads();   // Rs ready

    // ---- epilogue by lower waves: D row=(lane>>4)*4+reg, col=lane&15 ----
    if (kh == 0) {
#pragma unroll
      for (int i = 0; i < 4; ++i) {
        if (i < nfrag) {
#pragma unroll
          for (int r = 0; r < 4; ++r) {
            int m = i * 16 + kq * 4 + r;
            if (m < mcount) {
              out[(size_t)rowlist_s[m0 + m] * OUT_F + obase + w8 * 16 + nl] =
                  acc[i][r] + Rs[w8][m][nl] + bv;
            }
          }
        }
      }
    }

    if (m0 + MCH < count) {   // re-prime for the (rare) next chunk; L2-hot
#pragma unroll
      for (int j = 0; j < 3; ++j) {
        pa[j] = *(const float4*)(wp + j * 32);
        pb[j] = *(const float4*)(wp + j * 32 + 4);
      }
    }
  }
}

extern "C" void kernel_launch(void* const* d_in, const int* in_sizes, int n_in,
                              void* d_out, int out_size, void* d_ws, size_t ws_size,
                              hipStream_t stream) {
  const int*   which = (const int*)d_in[0];
  const float* x     = (const float*)d_in[1];
  const float* w     = (const float*)d_in[2];
  const float* b     = (const float*)d_in[3];
  float*       out   = (float*)d_out;

  dim3 grid(OUT_F / BN * NAGENT);   // 256 blocks, 1 per CU (swizzled decode)
  agent_linear_mfma8<<<grid, dim3(1024), 0, stream>>>(which, x, w, b, out);
}

// Round 8
// 108.939 us; speedup vs baseline: 1.1273x; 1.1273x over previous
//
#include <hip/hip_runtime.h>

// MultiAgentLinearLayer via bf16 MFMA, round 9: kh-split ACROSS blocks,
// 2 independent blocks/CU, atomic cross-half reduction.
// out[b,o] = sum_k W[agent[b],o,k]*x[b,k] + bias[agent[b],o]
// B=2048, I=O=512, 64 agents, fp32 in/out. Threshold 5.97e-2 permits bf16.
//
// R7 counters (first real ones): kernel latency-bound — MfmaUtil 0.9%,
// VALUBusy 5%, Occupancy 31%, HBM 825 GB/s (10%), FETCH 35MB => W is mostly
// L2/L3-resident; the HBM-floor model was wrong. One 1024-thread block/CU
// means every __syncthreads stalls all 16 waves. R8's global A-frag gathers
// stalled the K-loop (41-48us) — reverted to LDS Xs path.
// R9: 512-thread blocks (8 n-waves x 16 cols, BN=128), one K-half each.
// Grid = 4 nt x 2 kh x 64 agents = 512 blocks = 2/CU: same 16 waves/CU as
// R4, same total staging work (8 blocks x half-K == 4 x full-K), but when
// one block barriers, the co-resident block keeps issuing. Cross-half
// reduction via fp32 atomicAdd to zeroed out (2 commutative adds/elem =>
// deterministic); Rs LDS + park barrier deleted. LDS ~42KB => 2 blocks fit.
// Kept: XCD swizzle (agent's 8 blocks share bid%8), cvt_pk RNE packing,
// nfrag guard, stride-pad Xs (2-way conflicts = free), 3-deep W prime,
// which-first.

constexpr int BATCH  = 2048;
constexpr int NAGENT = 64;
constexpr int IN_F   = 512;
constexpr int OUT_F  = 512;

constexpr int BN  = 128;        // block n-tile (8 waves x 16 cols)
constexpr int KH  = 256;        // K-half per block
constexpr int MCH = 64;         // m rows per chunk (count<=64 in practice)
constexpr int XS2 = KH + 8;     // Xs stride in bf16 elems (264)

typedef __attribute__((ext_vector_type(8))) short short8;     // bf16 A/B frag
typedef __attribute__((ext_vector_type(4))) float f32x4;      // fp32 C/D frag
typedef __attribute__((ext_vector_type(4))) unsigned int u32x4;
typedef __bf16 bf16x2 __attribute__((ext_vector_type(2)));

__device__ inline unsigned pk_bf(float lo, float hi) {
  bf16x2 v;
  v[0] = (__bf16)lo;
  v[1] = (__bf16)hi;
  return __builtin_bit_cast(unsigned, v);   // v_cvt_pk_bf16_f32, RNE
}

__global__ __launch_bounds__(512, 4) void agent_linear_mfma9(
    const int*   __restrict__ which,
    const float* __restrict__ x,
    const float* __restrict__ weight,
    const float* __restrict__ bias,
    float*       __restrict__ out) {
  const int tid  = threadIdx.x;
  const int lane = tid & 63;
  const int wid  = tid >> 6;         // 0..7 (n-wave)

  // bid = (a&7) + 8*(nt + 4*khb) + 64*(a>>3): agent a's 8 blocks share bid%8
  const int bid   = blockIdx.x;      // 0..511
  const int agent = (bid & 7) | ((bid >> 6) << 3);
  const int sel   = (bid >> 3) & 7;
  const int nt    = sel & 3;
  const int khb   = sel >> 2;        // k-half of this block
  const int obase = nt * BN;
  const int kbase = khb * KH;

  __shared__ int wsum_s[8];
  __shared__ int rowlist_s[BATCH];                        // 8 KB
  __shared__ __align__(16) unsigned short Xs[MCH * XS2];  // 33 KB bf16

  // ---- issue `which` load first (longest dependent chain) ----
  const int4 v = ((const int4*)which)[tid];               // 4 vals/thread

  const int nl = lane & 15;      // n within frag / m within A-frag
  const int kq = lane >> 4;      // k-quad 0..3

  const float* wp = weight + ((size_t)(agent * OUT_F + obase + wid * 16 + nl)) * IN_F
                  + kbase + kq * 8;

  // ---- prime 3-deep W prefetch ----
  float4 pa[3], pb[3];
#pragma unroll
  for (int j = 0; j < 3; ++j) {
    pa[j] = *(const float4*)(wp + j * 32);
    pb[j] = *(const float4*)(wp + j * 32 + 4);
  }

  const float bv = bias[agent * OUT_F + obase + wid * 16 + nl];

  // ---- stable compaction: rows with which[i]==agent, ascending ----
  int m0_ = (v.x == agent), m1_ = (v.y == agent),
      m2_ = (v.z == agent), m3_ = (v.w == agent);
  int lc = m0_ + m1_ + m2_ + m3_;
  int s = lc;
#pragma unroll
  for (int off = 1; off < 64; off <<= 1) {
    int t = __shfl_up(s, off);
    if (lane >= off) s += t;
  }
  if (lane == 63) wsum_s[wid] = s;
  __syncthreads();
  int base = 0, count = 0;
#pragma unroll
  for (int w = 0; w < 8; ++w) {
    int ws = wsum_s[w];
    if (w < wid) base += ws;
    count += ws;
  }
  {
    int pos = base + s - lc;
    int i0 = 4 * tid;
    if (m0_) rowlist_s[pos++] = i0;
    if (m1_) rowlist_s[pos++] = i0 + 1;
    if (m2_) rowlist_s[pos++] = i0 + 2;
    if (m3_) rowlist_s[pos]   = i0 + 3;
  }

  for (int m0 = 0; m0 < count; m0 += MCH) {
    const int mcount = min(MCH, count - m0);
    const int nfrag  = (mcount + 15) >> 4;   // live 16-row A-frags (1..4)

    __syncthreads();   // iter0: rowlist ready; later: prior Xs reads done

    // ---- stage X chunk, this K-half only: 64 rows x 256 k as bf16 ----
    // idx = t*512+tid; r = idx>>6 (64 float4-cols per row); c4 = idx&63
#pragma unroll
    for (int t = 0; t < 8; ++t) {
      int idx = t * 512 + tid;
      int r   = idx >> 6;
      int c4  = idx & 63;
      if (r < mcount) {
        float4 xv = *(const float4*)(x + (size_t)rowlist_s[m0 + r] * IN_F
                                       + kbase + c4 * 4);
        uint2 w2;
        w2.x = pk_bf(xv.x, xv.y);
        w2.y = pk_bf(xv.z, xv.w);
        *(uint2*)&Xs[r * XS2 + c4 * 4] = w2;
      }
    }
    __syncthreads();   // Xs ready

    // ---- barrier-free K-loop over this block's 256-k half ----
    f32x4 acc[4] = {{0.f,0.f,0.f,0.f},{0.f,0.f,0.f,0.f},
                    {0.f,0.f,0.f,0.f},{0.f,0.f,0.f,0.f}};
#pragma unroll
    for (int k = 0; k < 8; ++k) {
      float4 c0 = pa[k % 3], c1 = pb[k % 3];
      if (k + 3 < 8) {
        pa[k % 3] = *(const float4*)(wp + (k + 3) * 32);
        pb[k % 3] = *(const float4*)(wp + (k + 3) * 32 + 4);
      }
      u32x4 q;
      q[0] = pk_bf(c0.x, c0.y); q[1] = pk_bf(c0.z, c0.w);
      q[2] = pk_bf(c1.x, c1.y); q[3] = pk_bf(c1.z, c1.w);
      short8 bfr = __builtin_bit_cast(short8, q);
#pragma unroll
      for (int i = 0; i < 4; ++i) {
        if (i < nfrag) {   // wave-uniform: skip dead-row frags
          short8 af = *(const short8*)&Xs[(i * 16 + nl) * XS2 + k * 32 + kq * 8];
          acc[i] = __builtin_amdgcn_mfma_f32_16x16x32_bf16(af, bfr, acc[i], 0, 0, 0);
        }
      }
    }

    // ---- epilogue: atomic add partial (+bias once, from kh0 block) ----
    // D row=(lane>>4)*4+reg (=m), col=lane&15 (=n). out zeroed by host-side
    // hipMemsetAsync; exactly 2 commutative fp32 adds per element.
    const float badd = (khb == 0) ? bv : 0.f;
#pragma unroll
    for (int i = 0; i < 4; ++i) {
      if (i < nfrag) {
#pragma unroll
        for (int r = 0; r < 4; ++r) {
          int m = i * 16 + kq * 4 + r;
          if (m < mcount) {
            atomicAdd(&out[(size_t)rowlist_s[m0 + m] * OUT_F + obase + wid * 16 + nl],
                      acc[i][r] + badd);
          }
        }
      }
    }

    if (m0 + MCH < count) {   // re-prime for the (rare) next chunk; L2-hot
#pragma unroll
      for (int j = 0; j < 3; ++j) {
        pa[j] = *(const float4*)(wp + j * 32);
        pb[j] = *(const float4*)(wp + j * 32 + 4);
      }
    }
  }
}

extern "C" void kernel_launch(void* const* d_in, const int* in_sizes, int n_in,
                              void* d_out, int out_size, void* d_ws, size_t ws_size,
                              hipStream_t stream) {
  const int*   which = (const int*)d_in[0];
  const float* x     = (const float*)d_in[1];
  const float* w     = (const float*)d_in[2];
  const float* b     = (const float*)d_in[3];
  float*       out   = (float*)d_out;

  // out accumulated via atomicAdd -> must start at zero (capture-legal async memset)
  hipMemsetAsync(d_out, 0, out_size, stream);

  dim3 grid(4 * 2 * NAGENT);   // 512 blocks = 2 per CU (swizzled decode)
  agent_linear_mfma9<<<grid, dim3(512), 0, stream>>>(which, x, w, b, out);
}

// Round 10
// 104.206 us; speedup vs baseline: 1.1785x; 1.0454x over previous
//
#include <hip/hip_runtime.h>

// MultiAgentLinearLayer via bf16 MFMA — FINAL: exact round-2-measured kernel
// (104.6us, best). R9's restore failed ONLY because the launcher used the
// old 2-D grid while the body decodes a 1-D swizzled blockIdx.x; fixed here
// (grid = 256 blocks, 1-D). Body is byte-identical to the Round-2 pass.
//
// Evidence ledger: R6 deeper prime: neutral; R7 pipelined staging: neutral;
// R9 kh-split 2 blocks/CU + atomics: overlap~0, -4us; R5 8 waves/CU: -9us;
// R8 global A-frags: -18us. R7 counters: MfmaUtil 0.9%, VALUBusy 5%, Occ 31%,
// HBM 10% => latency-bound plateau; dur_us floor = ~83us harness poison
// fills + ~21.5us kernel.
//
// out[b,o] = sum_k W[agent[b],o,k]*x[b,k] + bias[agent[b],o]
// B=2048, I=O=512, 64 agents, fp32 in/out. Threshold 5.97e-2 permits bf16.
// Structure: 1024 threads = 16 waves, 256 blocks (1/CU); waves 0..7 n-waves
// over BN=128 cols with K-half [0,256), waves 8..15 K-half [256,512);
// partials merged via padded LDS Rs (stride 17). X staged once to LDS bf16
// (stride 520, conflict-free b128 A-frag reads). W streamed global->reg,
// 3-deep float4x2 prefetch. fp32->bf16 via v_cvt_pk_bf16_f32 (RNE).
// nfrag guard skips dead 16-row A-frags. XCD swizzle: agent's 4 n-tiles
// share bid%8.

constexpr int BATCH  = 2048;
constexpr int NAGENT = 64;
constexpr int IN_F   = 512;
constexpr int OUT_F  = 512;

constexpr int BN  = 128;        // block n-tile
constexpr int MCH = 64;         // m rows per chunk (count<=64 in practice)
constexpr int XS  = IN_F + 8;   // X LDS stride in bf16 elems (520)

typedef __attribute__((ext_vector_type(8))) short short8;     // bf16 A/B frag
typedef __attribute__((ext_vector_type(4))) float f32x4;      // fp32 C/D frag
typedef __attribute__((ext_vector_type(4))) unsigned int u32x4;
typedef __bf16 bf16x2 __attribute__((ext_vector_type(2)));

__device__ inline unsigned pk_bf(float lo, float hi) {
  bf16x2 v;
  v[0] = (__bf16)lo;
  v[1] = (__bf16)hi;
  return __builtin_bit_cast(unsigned, v);   // v_cvt_pk_bf16_f32, RNE
}

__global__ __launch_bounds__(1024, 4) void agent_linear_mfma4(
    const int*   __restrict__ which,
    const float* __restrict__ x,
    const float* __restrict__ weight,
    const float* __restrict__ bias,
    float*       __restrict__ out) {
  const int tid   = threadIdx.x;
  const int lane  = tid & 63;
  const int wid   = tid >> 6;        // 0..15
  const int w8    = wid & 7;         // n-wave within BN
  const int kh    = wid >> 3;        // k-half: 0 or 1

  // bid = (a&7) + 8*n + 32*(a>>3): agent a's 4 n-tiles all share bid%8
  const int bid   = blockIdx.x;      // 0..255 (1-D grid REQUIRED)
  const int agent = (bid & 7) | ((bid >> 5) << 3);
  const int obase = ((bid >> 3) & 3) * BN;

  __shared__ int rowlist_s[BATCH];                       // 8 KB
  __shared__ int wsum_s[16];
  __shared__ __align__(16) unsigned short Xs[MCH * XS];  // 65 KB bf16
  __shared__ float Rs[8][MCH][17];                       // 34 KB, k-half partials

  const int nl = lane & 15;      // n within frag / m within A-frag
  const int kq = lane >> 4;      // k-quad 0..3

  const float* wp = weight + ((size_t)(agent * OUT_F + obase + w8 * 16 + nl)) * IN_F
                  + kh * 256 + kq * 8;

  // ---- prime 3-deep W prefetch: HBM latency hides under compact+stage ----
  float4 pa[3], pb[3];
#pragma unroll
  for (int j = 0; j < 3; ++j) {
    pa[j] = *(const float4*)(wp + j * 32);
    pb[j] = *(const float4*)(wp + j * 32 + 4);
  }

  const float bv = bias[agent * OUT_F + obase + w8 * 16 + nl];

  // ---- stable compaction: rows with which[i]==agent, ascending ----
  int2 v = ((const int2*)which)[tid];                    // 2 vals/thread
  int lc = (v.x == agent) + (v.y == agent);
  int s = lc;
#pragma unroll
  for (int off = 1; off < 64; off <<= 1) {
    int t = __shfl_up(s, off);
    if (lane >= off) s += t;
  }
  if (lane == 63) wsum_s[wid] = s;
  __syncthreads();
  int base = 0, count = 0;
#pragma unroll
  for (int w = 0; w < 16; ++w) {
    int ws = wsum_s[w];
    if (w < wid) base += ws;
    count += ws;
  }
  {
    int pos = base + s - lc;
    if (v.x == agent) rowlist_s[pos++] = 2 * tid;
    if (v.y == agent) rowlist_s[pos]   = 2 * tid + 1;
  }
  __syncthreads();   // rowlist ready

  for (int m0 = 0; m0 < count; m0 += MCH) {
    const int mcount = min(MCH, count - m0);
    const int nfrag  = (mcount + 15) >> 4;   // live 16-row A-frags (1..4)

    // ---- stage X chunk: only live rows ----
#pragma unroll
    for (int t = 0; t < 8; ++t) {
      int idx = t * 1024 + tid;
      int r   = idx >> 7;          // 0..63 (wave-uniform per t)
      int c4  = idx & 127;         // float4 column
      if (r < mcount) {
        float4 xv = *(const float4*)(x + (size_t)rowlist_s[m0 + r] * IN_F + c4 * 4);
        uint2 w2;
        w2.x = pk_bf(xv.x, xv.y);
        w2.y = pk_bf(xv.z, xv.w);
        *(uint2*)&Xs[r * XS + c4 * 4] = w2;
      }
    }
    __syncthreads();   // Xs ready

    // ---- barrier-free K-loop over this wave's 256-k half ----
    f32x4 acc[4] = {{0.f,0.f,0.f,0.f},{0.f,0.f,0.f,0.f},
                    {0.f,0.f,0.f,0.f},{0.f,0.f,0.f,0.f}};
    const int kbase = kh * 256;
#pragma unroll
    for (int k = 0; k < 8; ++k) {
      float4 c0 = pa[k % 3], c1 = pb[k % 3];
      if (k + 3 < 8) {
        pa[k % 3] = *(const float4*)(wp + (k + 3) * 32);
        pb[k % 3] = *(const float4*)(wp + (k + 3) * 32 + 4);
      }
      u32x4 q;
      q[0] = pk_bf(c0.x, c0.y); q[1] = pk_bf(c0.z, c0.w);
      q[2] = pk_bf(c1.x, c1.y); q[3] = pk_bf(c1.z, c1.w);
      short8 bfr = __builtin_bit_cast(short8, q);
#pragma unroll
      for (int i = 0; i < 4; ++i) {
        if (i < nfrag) {   // wave-uniform: skip dead-row frags entirely
          short8 af = *(const short8*)&Xs[(i * 16 + nl) * XS + kbase + k * 32 + kq * 8];
          acc[i] = __builtin_amdgcn_mfma_f32_16x16x32_bf16(af, bfr, acc[i], 0, 0, 0);
        }
      }
    }

    // ---- cross-k-half reduction: upper waves park partials in LDS ----
    if (kh == 1) {
#pragma unroll
      for (int i = 0; i < 4; ++i)
        if (i < nfrag)
#pragma unroll
          for (int r = 0; r < 4; ++r)
            Rs[w8][i * 16 + kq * 4 + r][nl] = acc[i][r];
    }
    __syncthreads();   // Rs ready; all Xs reads of this chunk also complete

    // ---- epilogue by lower waves: D row=(lane>>4)*4+reg, col=lane&15 ----
    if (kh == 0) {
#pragma unroll
      for (int i = 0; i < 4; ++i) {
        if (i < nfrag) {
#pragma unroll
          for (int r = 0; r < 4; ++r) {
            int m = i * 16 + kq * 4 + r;
            if (m < mcount) {
              out[(size_t)rowlist_s[m0 + m] * OUT_F + obase + w8 * 16 + nl] =
                  acc[i][r] + Rs[w8][m][nl] + bv;
            }
          }
        }
      }
    }

    if (m0 + MCH < count) {   // re-prime for the (rare) next chunk; L2-hot
#pragma unroll
      for (int j = 0; j < 3; ++j) {
        pa[j] = *(const float4*)(wp + j * 32);
        pb[j] = *(const float4*)(wp + j * 32 + 4);
      }
    }
  }
}

extern "C" void kernel_launch(void* const* d_in, const int* in_sizes, int n_in,
                              void* d_out, int out_size, void* d_ws, size_t ws_size,
                              hipStream_t stream) {
  const int*   which = (const int*)d_in[0];
  const float* x     = (const float*)d_in[1];
  const float* w     = (const float*)d_in[2];
  const float* b     = (const float*)d_in[3];
  float*       out   = (float*)d_out;

  // 1-D grid: 256 blocks, decoded via the XCD swizzle inside the kernel.
  dim3 grid(OUT_F / BN * NAGENT);
  agent_linear_mfma4<<<grid, dim3(1024), 0, stream>>>(which, x, w, b, out);
}